// Round 2
// baseline (65.728 us; speedup 1.0000x reference)
//
#include <hip/hip_runtime.h>
#include <math.h>

#define MAXP 32
#define BLOCKS 2048
#define WAVES_PER_BLOCK 4

__global__ __launch_bounds__(256, 8) void pfn_kernel(
    const float* __restrict__ voxels,
    const int*   __restrict__ num_points,
    const int*   __restrict__ coords,
    const float* __restrict__ W,
    const float* __restrict__ gamma,
    const float* __restrict__ beta,
    const float* __restrict__ rmean,
    const float* __restrict__ rvar,
    float*       __restrict__ out,
    int N)
{
    __shared__ float lds[WAVES_PER_BLOCK][MAXP * 4];

    const int tid  = threadIdx.x;
    const int lane = tid & 63;
    const int wid  = tid >> 6;
    float4* myLds = (float4*)lds[wid];           // wave-private 512B

    // ---- per-lane (= per output channel) constants: hoisted, once per wave ----
    const int d = lane;
    const float w0 = W[0*64+d], w1 = W[1*64+d], w2 = W[2*64+d];
    const float w3 = W[3*64+d], w4 = W[4*64+d], w5 = W[5*64+d];
    const float w6 = W[6*64+d], w7 = W[7*64+d], w8 = W[8*64+d];
    const float inv   = gamma[d] * rsqrtf(rvar[d] + 1e-3f);
    const float shift = fmaf(-rmean[d], inv, beta[d]);
    const float A  = (w0 + w4 + w7) * inv;   // coeff of x
    const float B  = (w1 + w5 + w8) * inv;   // coeff of y
    const float C  = (w2 + w6) * inv;        // coeff of z
    const float Dk = w3 * inv;               // coeff of w
    const float P4 = w4 * inv, P5 = w5 * inv, P6 = w6 * inv;
    const float P7 = w7 * inv, P8 = w8 * inv;

    const int wave_id = blockIdx.x * WAVES_PER_BLOCK + wid;
    const int Wstride = gridDim.x * WAVES_PER_BLOCK;   // 8192 waves

    int pillar = wave_id;

    // ---- prologue: loads for first pillar ----
    float4 q4n = make_float4(0.f, 0.f, 0.f, 0.f);
    int    npn = 0;
    int    c0n = 0, c1n = 0;
    if (pillar < N) {
        const float4* src = (const float4*)(voxels + (size_t)pillar * (MAXP * 4));
        q4n = src[lane & 31];
        npn = num_points[pillar];
        c0n = coords[pillar * 3 + 0];
        c1n = coords[pillar * 3 + 1];
    }

    while (pillar < N) {
        const float4 q  = q4n;
        const int    np = npn;
        const float  cx = fmaf((float)c0n, 0.2f, 0.1f);     // VX/2 + 0
        const float  cy = fmaf((float)c1n, 0.2f, -25.5f);   // VY/2 - 25.6

        // stage to wave-private LDS (lanes l and l+32 write same data: benign)
        myLds[lane & 31] = q;

        // butterfly over 32-lane groups: sums of x,y,z over ALL 32 pts
        float sx = q.x, sy = q.y, sz = q.z;
        #pragma unroll
        for (int msk = 1; msk < 32; msk <<= 1) {
            sx += __shfl_xor(sx, msk);
            sy += __shfl_xor(sy, msk);
            sz += __shfl_xor(sz, msk);
        }

        // prefetch next pillar (VMEM in flight under this pillar's compute)
        const int next = pillar + Wstride;
        if (next < N) {
            const float4* src = (const float4*)(voxels + (size_t)next * (MAXP * 4));
            q4n = src[lane & 31];
            npn = num_points[next];
            c0n = coords[next * 3 + 0];
            c1n = coords[next * 3 + 1];
        }

        const float rnf = 1.0f / (float)np;
        const float E   = shift - (sx*P4 + sy*P5 + sz*P6) * rnf - cx*P7 - cy*P8;

        // wait for ds_write + shuffles before cross-lane LDS reads
        asm volatile("s_waitcnt lgkmcnt(0)" ::: "memory");

        // masked (padded) points contribute exactly `shift`
        float m = (np < MAXP) ? shift : -INFINITY;

        #pragma unroll 4
        for (int p = 0; p < np; ++p) {       // np wave-uniform
            const float4 t = myLds[p];       // broadcast ds_read_b128
            float v = fmaf(t.x, A, E);
            v = fmaf(t.y, B, v);
            v = fmaf(t.z, C, v);
            v = fmaf(t.w, Dk, v);
            m = fmaxf(m, v);
        }

        out[(size_t)pillar * 64 + d] = fmaxf(m, 0.0f);   // relu(max) == max(relu)
        pillar = next;
    }
}

extern "C" void kernel_launch(void* const* d_in, const int* in_sizes, int n_in,
                              void* d_out, int out_size, void* d_ws, size_t ws_size,
                              hipStream_t stream) {
    const float* voxels     = (const float*)d_in[0];
    const int*   num_points = (const int*)  d_in[1];
    const int*   coords     = (const int*)  d_in[2];
    const float* W          = (const float*)d_in[3];
    const float* gamma      = (const float*)d_in[4];
    const float* beta       = (const float*)d_in[5];
    const float* rmean      = (const float*)d_in[6];
    const float* rvar       = (const float*)d_in[7];
    float*       out        = (float*)d_out;

    const int N = in_sizes[1];  // num_points: one entry per pillar
    pfn_kernel<<<BLOCKS, 256, 0, stream>>>(voxels, num_points, coords, W,
                                           gamma, beta, rmean, rvar, out, N);
}